// Round 7
// baseline (1155.613 us; speedup 1.0000x reference)
//
#include <hip/hip_runtime.h>
#include <hip/hip_bf16.h>

// Problem constants (fixed shapes from the reference)
#define M_ROWS 25088   // 8 * 3136 embedding rows
#define N_CENT 4096    // centroids
#define K_DIM  1536    // feature dim (elements == bytes in fp8)

// 256x256 tile, 8 waves (512 thr), wave = 128x64 output, BK=128 B, 8-phase
// schedule, double-buffered LDS 2 x 64 KB.
#define BM 256
#define BN 256
#define BKB 128                // fp8 bytes per K-tile
#define NKT (K_DIM / BKB)      // 12 K-tiles
#define ITERS (NKT / 2)        // 6 iterations x 2 tiles
#define AREG  32768            // one operand region per buffer (256 rows x 128 B)
#define BUFSZ 65536            // buffer = A region + B region

typedef __attribute__((ext_vector_type(8)))  int   int8v;    // f8f6f4 A/B frag (32 fp8)
typedef __attribute__((ext_vector_type(4)))  int   int4v;
typedef __attribute__((ext_vector_type(16))) float floatx16; // 32x32 MFMA accumulator

typedef __attribute__((address_space(1))) const void gvoid;
typedef __attribute__((address_space(3))) void lvoid;

// Wave-per-row convert: fp32 -> fp8 e4m3 (OCP, HW cvt) + fp32 sum-of-squares.
// (unchanged - proven at 436.5 us)
__global__ __launch_bounds__(256) void convert_rows(
    const float* __restrict__ src, unsigned int* __restrict__ dst,
    float* __restrict__ norms, unsigned int* __restrict__ minbuf, int nrows)
{
    const int row  = blockIdx.x * 4 + (threadIdx.x >> 6);
    const int lane = threadIdx.x & 63;
    if (row >= nrows) return;

    const float4* s = (const float4*)(src + (size_t)row * K_DIM);
    unsigned int* d = dst + (size_t)row * (K_DIM / 4);

    float4 v[6];
    #pragma unroll
    for (int j = 0; j < 6; ++j) v[j] = s[lane + j * 64];

    float ssq = 0.f;
    #pragma unroll
    for (int j = 0; j < 6; ++j) {
        ssq += v[j].x * v[j].x + v[j].y * v[j].y + v[j].z * v[j].z + v[j].w * v[j].w;
        int u = __builtin_amdgcn_cvt_pk_fp8_f32(v[j].x, v[j].y, 0, false);
        u     = __builtin_amdgcn_cvt_pk_fp8_f32(v[j].z, v[j].w, u, true);
        d[lane + j * 64] = (unsigned int)u;
    }

    #pragma unroll
    for (int off = 32; off >= 1; off >>= 1) ssq += __shfl_down(ssq, off, 64);
    if (lane == 0) {
        norms[row] = ssq;
        if (minbuf) minbuf[row] = 0x7F800000u;  // +inf bits
    }
}

// ---------------------------------------------------------------------------
// 8-phase 256x256 MX-fp8 GEMM with fused per-row min(dist^2) epilogue.
//
// R7 = R6 (passed, absmax 0.25) MINUS the sched_barrier(0) walls.
// Differential evidence: R1 (no walls, acc=128) -> no spill; R4/R6 (walls,
// same acc) -> 1.4-1.5 GB scratch spill, MfmaUtil 7.8%. The walls regionize
// the allocator (~10 regions/phase x 8 phases) and it spills; they are NOT
// needed for correctness:
//  * s_barrier has unmodeled side effects -> memory ops (ds_read,
//    global_load_lds) never cross it; region-counted vmcnt stays valid.
//  * "memory"-clobbered s_waitcnt asm orders all memory ops.
//  * The one real hazard - register-only MFMA hoisted past lgkmcnt(0)
//    (rule #18) - is covered by the ONE kept sched_barrier(0) after each
//    lgkm wait. This is exactly the guide's proven m201 template form.
// R5's failure is attributed to the global_load_lds offset-imm path, which
// stays avoided via laundered addressing (kept from R6).
//
// Addressing (R6-validated): 8 persistent per-lane pointers ({A,B} x
// {h0,h1} x {r0,r8}), advanced +=256 B/iter. Per-site tau offsets
// (+128/+256/+384) are IR adds laundered via asm("+v") BEFORE the
// intrinsic; offset arg ALWAYS 0 (R4-proven instruction form; also blocks
// folding into the unproven offset-imm field).
//
// Waits counted by BARRIER-DELIMITED REGION (permutation-proof):
//   prologue: vmcnt(0)  (single region)
//   p3: vmcnt(2) [last iter: 0]   p7: vmcnt(2)
// Steady p3 regions: [p0: 2xA@+128][p1: 2xA@+128 + 2xB@+256][p2: 2xB@+256];
// after vmcnt(2) only p2's 2 loads may remain -> all tile-t+1 A landed; its
// B was staged >=4 regions earlier. Same shape at p7 for tile t+2. Valid
// under ANY intra-region load permutation (loads cannot cross barriers).
//
// Stage placement (iteration it = tiles t=2it buf0 p0-3, t+1 buf1 p4-7;
// pointer base = tile 2it):
//   p0: A->buf1 h0 +128              p4: A->buf0 h0 +256
//   p1: A->buf1 h1 +128, B->buf0 h0 +256
//                                     p5: A->buf0 h1 +256, B->buf1 h0 +384
//   p2: B->buf0 h1 +256              p6: B->buf1 h1 +384
// Write-after-read: each stage issues after the closing barrier of the phase
// in which its dest region was last ds_read; per-wave lgkmcnt(0) precedes
// every closing barrier, so all waves' reads drained before any overwrite.
//
// Sigma swizzle (T2, rule #21 both-sides, R1/R4/R6-validated): physical =
// logical ^ (((logical>>7)&7)<<4) per operand region. Stage keeps LINEAR
// LDS dest; global SOURCE granule pre-swizzled: g = (lane&7) ^ (lane>>3).
// Frag reads apply sigma on the address (key (rl&7)<<4; second b128 at
// ^16); every wave read touches each 16-B granule with exactly 8 lanes.
// ---------------------------------------------------------------------------

__device__ __forceinline__ int8v ldfrag(const unsigned char* Lb, int off) {
    const int4v lo = *(const int4v*)(Lb + off);
    const int4v hi = *(const int4v*)(Lb + (off ^ 16));
    return __builtin_shufflevector(lo, hi, 0, 1, 2, 3, 4, 5, 6, 7);
}

__device__ __forceinline__ floatx16 mfma8(int8v a, int8v b, floatx16 c) {
    return __builtin_amdgcn_mfma_scale_f32_32x32x64_f8f6f4(
        a, b, c, 0 /*cbsz e4m3*/, 0 /*blgp e4m3*/,
        0, 0x7F7F7F7F, 0, 0x7F7F7F7F);   // unit E8M0 scales
}

// one 1024-B stage: laundered address, offset imm ALWAYS 0 (R4-proven form)
#define STG1(P, OFF, L) do { \
    const unsigned char* _q = (P) + (OFF); \
    asm volatile("" : "+v"(_q)); \
    __builtin_amdgcn_global_load_lds((gvoid*)_q, (lvoid*)(L), 16, 0, 0); \
} while (0)

// stage one half-tile: 16 rows x 128 B via two 1 KB loads (r0, r8)
#define STG_A2(BUF, HH, OFF) do { \
    STG1(aP##HH##0, OFF, (char*)lds + (BUF) * BUFSZ + (HH) * 16384 + wave * 2048); \
    STG1(aP##HH##8, OFF, (char*)lds + (BUF) * BUFSZ + (HH) * 16384 + wave * 2048 + 1024); \
} while (0)
#define STG_B2(BUF, HH, OFF) do { \
    STG1(bP##HH##0, OFF, (char*)lds + (BUF) * BUFSZ + AREG + (HH) * 16384 + wave * 2048); \
    STG1(bP##HH##8, OFF, (char*)lds + (BUF) * BUFSZ + AREG + (HH) * 16384 + wave * 2048 + 1024); \
} while (0)

// R7: plain barrier / plain wait - NO sched_barrier walls (spill fix)
#define SBAR()   __builtin_amdgcn_s_barrier()
#define WAITV(N) asm volatile("s_waitcnt vmcnt(" #N ")" ::: "memory")

#define PHASE_TAIL(IM) \
    SBAR(); \
    asm volatile("s_waitcnt lgkmcnt(0)" ::: "memory"); \
    __builtin_amdgcn_sched_barrier(0); /* rule #18: MFMA must not hoist */ \
    __builtin_amdgcn_s_setprio(1); \
    acc[IM][0] = mfma8(a0, b00, acc[IM][0]); \
    acc[IM][0] = mfma8(a1, b01, acc[IM][0]); \
    acc[IM][1] = mfma8(a0, b10, acc[IM][1]); \
    acc[IM][1] = mfma8(a1, b11, acc[IM][1]); \
    __builtin_amdgcn_s_setprio(0); \
    SBAR()

// One K-tile = 4 phases. S0..S2 = stage statements. W3 = wait before p3's
// pre-MFMA barrier. B-frags (both k-subtiles, in=0,1) are read once in the
// tile's first phase and held in registers across the tile.
#define HALF_TILE(BUFOFF, S0, S1, S2, W3) do { \
    const unsigned char* Lb = (const unsigned char*)lds + (BUFOFF); \
    int8v b00 = ldfrag(Lb, bBase + kq0); \
    int8v b01 = ldfrag(Lb, bBase + kq1); \
    int8v b10 = ldfrag(Lb, bBase + 4096 + kq0); \
    int8v b11 = ldfrag(Lb, bBase + 4096 + kq1); \
    int8v a0  = ldfrag(Lb, aBase + kq0); \
    int8v a1  = ldfrag(Lb, aBase + kq1); \
    S0; \
    PHASE_TAIL(0); \
    a0 = ldfrag(Lb, aBase + 4096 + kq0);  a1 = ldfrag(Lb, aBase + 4096 + kq1); \
    S1; \
    PHASE_TAIL(1); \
    a0 = ldfrag(Lb, aBase + 8192 + kq0);  a1 = ldfrag(Lb, aBase + 8192 + kq1); \
    S2; \
    PHASE_TAIL(2); \
    a0 = ldfrag(Lb, aBase + 12288 + kq0); a1 = ldfrag(Lb, aBase + 12288 + kq1); \
    W3; \
    PHASE_TAIL(3); \
} while (0)

__global__ __launch_bounds__(512, 2) void gemm_min(
    const unsigned char* __restrict__ A,
    const unsigned char* __restrict__ B,
    const float* __restrict__ nx,
    const float* __restrict__ nc,
    unsigned int* __restrict__ minbuf)
{
    __shared__ __align__(16) unsigned char lds[2 * BUFSZ];   // 128 KB -> 1 block/CU

    const int tid  = threadIdx.x;
    const int wave = tid >> 6;
    const int lane = tid & 63;
    const int rl   = lane & 31;        // row (A) / col (B) within a 32-tile
    const int h    = lane >> 5;        // k-half selector within 64-B subtile
    const int wm   = wave >> 2;        // 0..1 : 128-row half of M-tile
    const int wn   = wave & 3;         // 0..3 : 64-col slice of N-tile
    const int tile_n = blockIdx.x * BN;
    const int tile_m = blockIdx.y * BM;

    // staging sources (sigma-preswizzled): row = wave*16 + lane>>3 within
    // the h-half; col granule = (lane&7) ^ (lane>>3). 8 persistent pointers,
    // advanced += 2*BKB per iteration (base tile = 2it).
    const int srow = wave * 16 + (lane >> 3);
    const int scol = (((lane & 7) ^ ((lane >> 3) & 7)) << 4);
    const unsigned char* aP00 = A + (size_t)(tile_m + srow) * K_DIM + scol;  // h0, r0
    const unsigned char* aP08 = aP00 + (size_t)8 * K_DIM;                    // h0, r8
    const unsigned char* aP10 = aP00 + (size_t)128 * K_DIM;                  // h1, r0
    const unsigned char* aP18 = aP10 + (size_t)8 * K_DIM;                    // h1, r8
    const unsigned char* bP00 = B + (size_t)(tile_n + srow) * K_DIM + scol;
    const unsigned char* bP08 = bP00 + (size_t)8 * K_DIM;
    const unsigned char* bP10 = bP00 + (size_t)128 * K_DIM;
    const unsigned char* bP18 = bP10 + (size_t)8 * K_DIM;

    // frag-read offsets (sigma applied): off = row*128 + ((s*64+h*32) ^ x),
    // x = (rl&7)<<4 (= row&7; tile offsets are multiples of 8 rows);
    // second b128 of a frag at off^16
    const int kq0 = (h * 32) ^ ((rl & 7) << 4);
    const int kq1 = kq0 ^ 64;
    const int aBase = (wm * 128 + rl) * 128;          // A region, + im*4096
    const int bBase = AREG + (wn * 64 + rl) * 128;    // B region, + in*4096

    floatx16 acc[4][2];
    #pragma unroll
    for (int im = 0; im < 4; ++im)
        #pragma unroll
        for (int in = 0; in < 2; ++in)
            #pragma unroll
            for (int k = 0; k < 16; ++k) acc[im][in][k] = 0.f;

    // prologue: stage tile0 A+B and tile1 B. Single region -> only vmcnt(0)
    // is permutation-safe; one-time cost.
    STG_A2(0, 0, 0);   STG_A2(0, 1, 0);
    STG_B2(0, 0, 0);   STG_B2(0, 1, 0);
    STG_B2(1, 0, 128); STG_B2(1, 1, 128);
    WAITV(0);
    SBAR();

    #pragma unroll 1   // MUST stay rolled (R6: full unroll spills)
    for (int it = 0; it < ITERS; ++it) {
        const bool more = (it < ITERS - 1);

        // tile t = 2it (buf0): phases 0-3
        HALF_TILE(0,
            { STG_A2(1, 0, 128); },
            { STG_A2(1, 1, 128); if (more) STG_B2(0, 0, 256); },
            { if (more) STG_B2(0, 1, 256); },
            { if (more) WAITV(2); else WAITV(0); });

        // tile t+1 (buf1): phases 4-7
        HALF_TILE(BUFSZ,
            { if (more) STG_A2(0, 0, 256); },
            { if (more) { STG_A2(0, 1, 256); STG_B2(1, 0, 384); } },
            { if (more) STG_B2(1, 1, 384); },
            { WAITV(2); });

        aP00 += 2 * BKB; aP08 += 2 * BKB; aP10 += 2 * BKB; aP18 += 2 * BKB;
        bP00 += 2 * BKB; bP08 += 2 * BKB; bP10 += 2 * BKB; bP18 += 2 * BKB;
    }

    // epilogue: dist^2 = nx[m] + nc[p] - 2*dot; per-row min over 256 cols.
    // C/D: col = rl, row = (r&3) + 8*(r>>2) + 4*h (+ im*32 + wm*128).
    float cn[2];
    #pragma unroll
    for (int in = 0; in < 2; ++in) cn[in] = nc[tile_n + wn * 64 + in * 32 + rl];

    #pragma unroll
    for (int im = 0; im < 4; ++im) {
        #pragma unroll
        for (int r = 0; r < 16; ++r) {
            float v = fminf(cn[0] - 2.f * acc[im][0][r],
                            cn[1] - 2.f * acc[im][1][r]);
            v = fminf(v, __shfl_xor(v, 16, 64));
            v = fminf(v, __shfl_xor(v, 8, 64));
            v = fminf(v, __shfl_xor(v, 4, 64));
            v = fminf(v, __shfl_xor(v, 2, 64));
            v = fminf(v, __shfl_xor(v, 1, 64));
            if (rl == 0) {
                const int row = tile_m + wm * 128 + im * 32
                              + (r & 3) + 8 * (r >> 2) + 4 * h;
                atomicMin(&minbuf[row], __float_as_uint(v + nx[row]));
            }
        }
    }
}

__global__ void finalize_kernel(const unsigned int* __restrict__ minbuf,
                                float* __restrict__ out)
{
    const int i = blockIdx.x * 256 + threadIdx.x;
    if (i == 0) out[0] = 0.0f;                 // loss (eval mode)
    if (i < M_ROWS) out[1 + i] = sqrtf(__uint_as_float(minbuf[i]));
}

extern "C" void kernel_launch(void* const* d_in, const int* in_sizes, int n_in,
                              void* d_out, int out_size, void* d_ws, size_t ws_size,
                              hipStream_t stream)
{
    const float* embeds = (const float*)d_in[0];   // [8, 3136, 1536] fp32
    const float* cents  = (const float*)d_in[1];   // [4096, 1536] fp32
    float* out = (float*)d_out;                    // [1 + 25088] fp32

    char* ws = (char*)d_ws;
    const size_t offA   = 0;                                   // 38,535,168 B (fp8)
    const size_t offB   = offA + (size_t)M_ROWS * K_DIM;       //  6,291,456 B (fp8)
    const size_t offNx  = offB + (size_t)N_CENT * K_DIM;       //    100,352 B
    const size_t offNc  = offNx + (size_t)M_ROWS * 4;          //     16,384 B
    const size_t offMin = offNc + (size_t)N_CENT * 4;          //    100,352 B

    unsigned char* A8 = (unsigned char*)(ws + offA);
    unsigned char* B8 = (unsigned char*)(ws + offB);
    float* nx = (float*)(ws + offNx);
    float* nc = (float*)(ws + offNc);
    unsigned int* minbuf = (unsigned int*)(ws + offMin);

    convert_rows<<<M_ROWS / 4, 256, 0, stream>>>(embeds, (unsigned int*)A8, nx, minbuf, M_ROWS);
    convert_rows<<<N_CENT / 4, 256, 0, stream>>>(cents, (unsigned int*)B8, nc, nullptr, N_CENT);

    dim3 grid(N_CENT / BN, M_ROWS / BM);   // (16, 98)
    gemm_min<<<grid, 512, 0, stream>>>(A8, B8, nx, nc, minbuf);

    finalize_kernel<<<(M_ROWS + 255) / 256, 256, 0, stream>>>(minbuf, out);
}

// Round 8
// 528.008 us; speedup vs baseline: 2.1886x; 2.1886x over previous
//
#include <hip/hip_runtime.h>
#include <hip/hip_bf16.h>

// Problem constants (fixed shapes from the reference)
#define M_ROWS 25088   // 8 * 3136 embedding rows
#define N_CENT 4096    // centroids
#define K_DIM  1536    // feature dim (elements == bytes in fp8)

// R8 GEMM: 128x128 tile, 4 waves (256 thr), wave = 64x64 output via
// 2x2 mfma_scale_f32_32x32x64, BK=64, TRIPLE-buffered LDS 3 x 16 KB = 48 KB
// -> ~3 blocks/CU (R0's proven multi-block overlap), counted vmcnt(4),
// ONE barrier per K-step (R0 had two + full drain).
#define TILE 128
#define BKT  64                 // fp8 bytes per K-step
#define NKT  (K_DIM / BKT)      // 24 K-steps
#define BUFB 16384              // one buffer: A 8KB + B 8KB
#define BREG 8192               // B region offset within a buffer

typedef __attribute__((ext_vector_type(8)))  int   int8v;    // f8f6f4 A/B frag (32 fp8)
typedef __attribute__((ext_vector_type(4)))  int   int4v;
typedef __attribute__((ext_vector_type(16))) float floatx16; // 32x32 MFMA accumulator

typedef __attribute__((address_space(1))) const void gvoid;
typedef __attribute__((address_space(3))) void lvoid;

// Wave-per-row convert: fp32 -> fp8 e4m3 (OCP, HW cvt) + fp32 sum-of-squares.
// (unchanged - proven at 436.5 us)
__global__ __launch_bounds__(256) void convert_rows(
    const float* __restrict__ src, unsigned int* __restrict__ dst,
    float* __restrict__ norms, unsigned int* __restrict__ minbuf, int nrows)
{
    const int row  = blockIdx.x * 4 + (threadIdx.x >> 6);
    const int lane = threadIdx.x & 63;
    if (row >= nrows) return;

    const float4* s = (const float4*)(src + (size_t)row * K_DIM);
    unsigned int* d = dst + (size_t)row * (K_DIM / 4);

    float4 v[6];
    #pragma unroll
    for (int j = 0; j < 6; ++j) v[j] = s[lane + j * 64];

    float ssq = 0.f;
    #pragma unroll
    for (int j = 0; j < 6; ++j) {
        ssq += v[j].x * v[j].x + v[j].y * v[j].y + v[j].z * v[j].z + v[j].w * v[j].w;
        int u = __builtin_amdgcn_cvt_pk_fp8_f32(v[j].x, v[j].y, 0, false);
        u     = __builtin_amdgcn_cvt_pk_fp8_f32(v[j].z, v[j].w, u, true);
        d[lane + j * 64] = (unsigned int)u;
    }

    #pragma unroll
    for (int off = 32; off >= 1; off >>= 1) ssq += __shfl_down(ssq, off, 64);
    if (lane == 0) {
        norms[row] = ssq;
        if (minbuf) minbuf[row] = 0x7F800000u;  // +inf bits
    }
}

// ---------------------------------------------------------------------------
// R8 gemm_min: R0's proven SHELL (128² tile, 4 waves, ~3 blocks/CU so
// inter-block TLP hides latency - the thing every 256² attempt lacked)
// + R1-validated 32x32x64 mfma_scale math/epilogue
// + R4-validated counted-vmcnt triple-buffer pipeline, sized to add ZERO
//   register pressure (R4-R7's fatal flaw: 8-phase frag liveness + 128 acc
//   at a 256-reg cap -> GB-scale spill).
//
// Pressure: acc[2][2]=64 + transient frags 32 + 4 stage ptrs 8 + offsets
// ~15 -> ~125 unified regs/wave -> 3 waves/SIMD, no spill. LDS 48 KB ->
// 3 blocks/CU.
//
// Schedule (one barrier per K-step):
//   iter t: [stage tile t+2: 4 loads] [8 ds_read_b128 -> 4 MFMA]
//           [lgkmcnt(0)] [vmcnt(4) | vmcnt(0) at tail] [s_barrier]
// Region ledger (loads can't cross barriers; permutation-proof within a
// region): one 4-load region per iter; after vmcnt(4) only the newest
// region (stage t+2) may be outstanding -> buf[(t+1)%3] fully landed
// before iter t+1 reads it. Prologue stages t=0,1 and drains vmcnt(0)
// once. Write-after-read: stage(t+3) overwrites buf[t%3] only at iter
// t+1, after barrier(t); the explicit per-wave lgkmcnt(0) before
// barrier(t) guarantees all ds_reads of buf[t%3] were SERVICED (not just
// issued) before any wave could cross and issue the overwriting DMA.
// Frag reads and MFMAs are plain IR ops in the same region (SSA dep ->
// compiler inserts exact lgkm waits; no rule-#18 exposure, no walls).
//
// LDS rotation swizzle at 64-B rows (4 granules/row, both-sides):
//   physical slot of logical granule c in row r = (c + r) & 3.
//   Stage: linear DMA dest (lane l -> row l>>2, slot l&3); global SOURCE
//   granule = ((l&3) - (l>>2)) & 3  [hand-checked: row 1 slots 0..3 hold
//   granules 3,0,1,2 -> read granule c at slot (c+1)&3 = formula].
//   Read (lane rl,h wants granules h*2, h*2+1 of row ..+rl; row&3 = rl&3):
//   slots (h*2+g+rl)&3. Per instruction each of the 8 16-B line positions
//   ((r&1)*4 + slot) gets exactly 8 lanes -> conflict-free (8-phase floor).
// ---------------------------------------------------------------------------

__device__ __forceinline__ int8v ldfrag(const unsigned char* p, int s0, int s1) {
    const int4v lo = *(const int4v*)(p + s0);   // logical granule c0 (16 B)
    const int4v hi = *(const int4v*)(p + s1);   // logical granule c0+1
    return __builtin_shufflevector(lo, hi, 0, 1, 2, 3, 4, 5, 6, 7);
}

__device__ __forceinline__ floatx16 mfma8(int8v a, int8v b, floatx16 c) {
    return __builtin_amdgcn_mfma_scale_f32_32x32x64_f8f6f4(
        a, b, c, 0 /*cbsz e4m3*/, 0 /*blgp e4m3*/,
        0, 0x7F7F7F7F, 0, 0x7F7F7F7F);   // unit E8M0 scales
}

// one 1024-B stage (16 rows x 64 B): laundered global addr (R6-proven form;
// offset imm stays 0 - never trust the unverified offset-imm path)
#define STG(P, OFF, LOFF) do { \
    const unsigned char* _q = (P) + (OFF); \
    asm volatile("" : "+v"(_q)); \
    __builtin_amdgcn_global_load_lds((gvoid*)_q, \
        (lvoid*)((char*)lds + (LOFF)), 16, 0, 0); \
} while (0)

#define WAITV(N) asm volatile("s_waitcnt vmcnt(" #N ")" ::: "memory")

__global__ __launch_bounds__(256) void gemm_min(
    const unsigned char* __restrict__ A,
    const unsigned char* __restrict__ B,
    const float* __restrict__ nx,
    const float* __restrict__ nc,
    unsigned int* __restrict__ minbuf)
{
    __shared__ __align__(16) unsigned char lds[3 * BUFB];   // 48 KB -> 3 blocks/CU

    const int tid  = threadIdx.x;
    const int wave = tid >> 6;         // 0..3
    const int lane = tid & 63;
    const int rl   = lane & 31;        // row (A) / col (B) within a 32-tile
    const int h    = lane >> 5;        // k-half selector (32 B each)
    const int wm   = (wave >> 1) * 64; // wave quadrant within 128x128
    const int wn   = (wave & 1) * 64;
    const int tile_n = blockIdx.x * TILE;
    const int tile_m = blockIdx.y * TILE;

    // staging sources (rotation-preswizzled): lane l -> row l>>2 of the
    // 16-row group, source granule ((l&3) - (l>>2)) & 3. Wave w covers rows
    // w*16..+16 (LDS w*1024) and rows 64+w*16 (LDS 4096 + w*1024).
    const int srow = wave * 16 + (lane >> 2);
    const int scol = ((((lane & 3) - ((lane >> 2) & 3)) & 3)) * 16;
    const unsigned char* aS0 = A + (size_t)(tile_m + srow) * K_DIM + scol;
    const unsigned char* aS1 = aS0 + (size_t)64 * K_DIM;
    const unsigned char* bS0 = B + (size_t)(tile_n + srow) * K_DIM + scol;
    const unsigned char* bS1 = bS0 + (size_t)64 * K_DIM;

    // frag-read addressing (rotation applied): row-byte bases + slot pair
    const int rowA0 = (wm + rl) * 64;             // im = 0
    const int rowA1 = (wm + 32 + rl) * 64;        // im = 1
    const int rowB0 = BREG + (wn + rl) * 64;      // in = 0
    const int rowB1 = BREG + (wn + 32 + rl) * 64; // in = 1
    const int s0 = ((h * 2 + rl) & 3) * 16;       // slot of granule h*2
    const int s1 = ((h * 2 + 1 + rl) & 3) * 16;   // slot of granule h*2+1

    floatx16 acc[2][2];
    #pragma unroll
    for (int im = 0; im < 2; ++im)
        #pragma unroll
        for (int in = 0; in < 2; ++in)
            #pragma unroll
            for (int k = 0; k < 16; ++k) acc[im][in][k] = 0.f;

    // prologue: stage K-steps 0 (buf0) and 1 (buf1); single drain + barrier
    STG(aS0, 0,  0     + wave * 1024);
    STG(aS1, 0,  4096  + wave * 1024);
    STG(bS0, 0,  BREG         + wave * 1024);
    STG(bS1, 0,  BREG + 4096  + wave * 1024);
    STG(aS0, BKT, BUFB         + wave * 1024);
    STG(aS1, BKT, BUFB + 4096  + wave * 1024);
    STG(bS0, BKT, BUFB + BREG        + wave * 1024);
    STG(bS1, BKT, BUFB + BREG + 4096 + wave * 1024);
    WAITV(0);
    __builtin_amdgcn_s_barrier();

    int curOff = 0;          // buffer holding K-step t
    int stgOff = 2 * BUFB;   // buffer receiving K-step t+2

    #pragma unroll 1   // MUST stay rolled (full unroll maxes VGPRs, spills)
    for (int t = 0; t < NKT; ++t) {
        const bool more2 = (t < NKT - 2);
        if (more2) {   // stage K-step t+2 (ptrs sit at step t -> +2*BKT)
            STG(aS0, 2 * BKT, stgOff        + wave * 1024);
            STG(aS1, 2 * BKT, stgOff + 4096 + wave * 1024);
            STG(bS0, 2 * BKT, stgOff + BREG        + wave * 1024);
            STG(bS1, 2 * BKT, stgOff + BREG + 4096 + wave * 1024);
        }

        const unsigned char* Lb = (const unsigned char*)lds + curOff;
        const int8v a0 = ldfrag(Lb + rowA0, s0, s1);
        const int8v a1 = ldfrag(Lb + rowA1, s0, s1);
        const int8v b0 = ldfrag(Lb + rowB0, s0, s1);
        const int8v b1 = ldfrag(Lb + rowB1, s0, s1);

        acc[0][0] = mfma8(a0, b0, acc[0][0]);
        acc[0][1] = mfma8(a0, b1, acc[0][1]);
        acc[1][0] = mfma8(a1, b0, acc[1][0]);
        acc[1][1] = mfma8(a1, b1, acc[1][1]);

        if (t < NKT - 1) {
            // lgkm drain: this wave's buf[t%3] ds_reads are SERVICED before
            // it can cross the barrier (write-after-read safety vs the
            // stage(t+3) DMA issued by other waves at iter t+1).
            asm volatile("s_waitcnt lgkmcnt(0)" ::: "memory");
            if (more2) { WAITV(4); }   // newest region (t+2) may stay in flight
            else       { WAITV(0); }   // tail drain
            __builtin_amdgcn_s_barrier();
        }

        aS0 += BKT; aS1 += BKT; bS0 += BKT; bS1 += BKT;
        curOff = (curOff == 2 * BUFB) ? 0 : curOff + BUFB;
        stgOff = (stgOff == 2 * BUFB) ? 0 : stgOff + BUFB;
    }

    // epilogue (R1-validated 32x32 C/D layout): col = rl,
    // row = (r&3) + 8*(r>>2) + 4*h  (+ im*32 + wm). Row lives in one
    // 32-lane half -> shfl_xor masks 16..1 (never cross bit 5).
    const float cn0 = nc[tile_n + wn + rl];
    const float cn1 = nc[tile_n + wn + 32 + rl];

    #pragma unroll
    for (int im = 0; im < 2; ++im) {
        #pragma unroll
        for (int r = 0; r < 16; ++r) {
            float v = fminf(cn0 - 2.f * acc[im][0][r],
                            cn1 - 2.f * acc[im][1][r]);
            v = fminf(v, __shfl_xor(v, 16, 64));
            v = fminf(v, __shfl_xor(v, 8, 64));
            v = fminf(v, __shfl_xor(v, 4, 64));
            v = fminf(v, __shfl_xor(v, 2, 64));
            v = fminf(v, __shfl_xor(v, 1, 64));
            if (rl == 0) {
                const int row = tile_m + wm + im * 32
                              + (r & 3) + 8 * (r >> 2) + 4 * h;
                atomicMin(&minbuf[row], __float_as_uint(v + nx[row]));
            }
        }
    }
}

__global__ void finalize_kernel(const unsigned int* __restrict__ minbuf,
                                float* __restrict__ out)
{
    const int i = blockIdx.x * 256 + threadIdx.x;
    if (i == 0) out[0] = 0.0f;                 // loss (eval mode)
    if (i < M_ROWS) out[1 + i] = sqrtf(__uint_as_float(minbuf[i]));
}

extern "C" void kernel_launch(void* const* d_in, const int* in_sizes, int n_in,
                              void* d_out, int out_size, void* d_ws, size_t ws_size,
                              hipStream_t stream)
{
    const float* embeds = (const float*)d_in[0];   // [8, 3136, 1536] fp32
    const float* cents  = (const float*)d_in[1];   // [4096, 1536] fp32
    float* out = (float*)d_out;                    // [1 + 25088] fp32

    char* ws = (char*)d_ws;
    const size_t offA   = 0;                                   // 38,535,168 B (fp8)
    const size_t offB   = offA + (size_t)M_ROWS * K_DIM;       //  6,291,456 B (fp8)
    const size_t offNx  = offB + (size_t)N_CENT * K_DIM;       //    100,352 B
    const size_t offNc  = offNx + (size_t)M_ROWS * 4;          //     16,384 B
    const size_t offMin = offNc + (size_t)N_CENT * 4;          //    100,352 B

    unsigned char* A8 = (unsigned char*)(ws + offA);
    unsigned char* B8 = (unsigned char*)(ws + offB);
    float* nx = (float*)(ws + offNx);
    float* nc = (float*)(ws + offNc);
    unsigned int* minbuf = (unsigned int*)(ws + offMin);

    convert_rows<<<M_ROWS / 4, 256, 0, stream>>>(embeds, (unsigned int*)A8, nx, minbuf, M_ROWS);
    convert_rows<<<N_CENT / 4, 256, 0, stream>>>(cents, (unsigned int*)B8, nc, nullptr, N_CENT);

    dim3 grid(N_CENT / TILE, M_ROWS / TILE);   // (32, 196); x = column tiles for A L2 reuse
    gemm_min<<<grid, 256, 0, stream>>>(A8, B8, nx, nc, minbuf);

    finalize_kernel<<<(M_ROWS + 255) / 256, 256, 0, stream>>>(minbuf, out);
}